// Round 10
// baseline (456.534 us; speedup 1.0000x reference)
//
#include <hip/hip_runtime.h>

#define T_LEN 512
#define HD    32
#define FUT   60
#define ELW   16      // batch elements per wave (16x16 MFMA tile)
#define WPB   8       // waves per block (2 per SIMD)

typedef float    f32x4 __attribute__((ext_vector_type(4)));
typedef _Float16 f16x2 __attribute__((ext_vector_type(2)));
typedef _Float16 f16x8 __attribute__((ext_vector_type(8)));
typedef unsigned int u32x2 __attribute__((ext_vector_type(2)));

union F16x8U { f16x8 v; f16x2 p[4]; unsigned int d[4]; };

#define MF(a, b, c) __builtin_amdgcn_mfma_f32_16x16x32_f16((a), (b), (c), 0, 0, 0)

#define L2E  1.4426950408889634f
#define N2E  2.8853900817779268f

__device__ __forceinline__ f16x2 pkrtz(float a, float b) {
    return __builtin_bit_cast(f16x2, __builtin_amdgcn_cvt_pkrtz(a, b));
}
__device__ __forceinline__ unsigned pkbits(float a, float b) {
    return __builtin_bit_cast(unsigned, __builtin_amdgcn_cvt_pkrtz(a, b));
}
__device__ __forceinline__ float dot2(f16x2 a, f16x2 b, float c) {
    return __builtin_amdgcn_fdot2(a, b, c, false);
}
__device__ __forceinline__ float exp2f_(float x) {
#if __has_builtin(__builtin_amdgcn_exp2f)
    return __builtin_amdgcn_exp2f(x);
#else
    return __builtin_exp2f(x);
#endif
}
// inputs PRESCALED: u = x*log2e -> sigmoid(x); u = x*2log2e -> tanh(x)
__device__ __forceinline__ float sig_s(float u) {
    return __builtin_amdgcn_rcpf(1.0f + exp2f_(-u));
}
__device__ __forceinline__ float tanh_s(float u) {
    return fmaf(2.0f, __builtin_amdgcn_rcpf(1.0f + exp2f_(-u)), -1.0f);
}

__device__ __forceinline__ void swap32(unsigned& a, unsigned& b) {
#if __has_builtin(__builtin_amdgcn_permlane32_swap)
    u32x2 r = __builtin_amdgcn_permlane32_swap(a, b, false, false);
    a = r.x; b = r.y;
#else
    unsigned as = __shfl_xor((int)a, 32, 64), bs = __shfl_xor((int)b, 32, 64);
    const bool hi = (threadIdx.x & 32) != 0;
    unsigned na = hi ? bs : a, nb = hi ? b : as;
    a = na; b = nb;
#endif
}
__device__ __forceinline__ void swap16(unsigned& a, unsigned& b) {
#if __has_builtin(__builtin_amdgcn_permlane16_swap)
    u32x2 r = __builtin_amdgcn_permlane16_swap(a, b, false, false);
    a = r.x; b = r.y;
#else
    unsigned as = __shfl_xor((int)a, 16, 64), bs = __shfl_xor((int)b, 16, 64);
    const bool hi = (threadIdx.x & 16) != 0;
    unsigned na = hi ? bs : a, nb = hi ? b : as;
    a = na; b = nb;
#endif
}

// A-fragment (row = l&15, k = 8*(l>>4)..+7) from row-major W[96][32], scaled
__device__ __forceinline__ f16x8 loadAfrag(const float* W, int rowoff, int s, int g, float sc) {
    const float* p = W + (size_t)(rowoff + s) * HD + g * 8;
    f32x4 a = *(const f32x4*)p;
    f32x4 b = *(const f32x4*)(p + 4);
    f16x8 r;
    r[0] = (_Float16)(a[0]*sc); r[1] = (_Float16)(a[1]*sc);
    r[2] = (_Float16)(a[2]*sc); r[3] = (_Float16)(a[3]*sc);
    r[4] = (_Float16)(b[0]*sc); r[5] = (_Float16)(b[1]*sc);
    r[6] = (_Float16)(b[2]*sc); r[7] = (_Float16)(b[3]*sc);
    return r;
}
__device__ __forceinline__ f16x8 loadAfragSum(const float* WA, const float* WB,
                                              int rowoff, int s, int g, float sc) {
    const float* pa = WA + (size_t)(rowoff + s) * HD + g * 8;
    const float* pb = WB + (size_t)(rowoff + s) * HD + g * 8;
    f32x4 a0 = *(const f32x4*)pa, a1 = *(const f32x4*)(pa + 4);
    f32x4 b0 = *(const f32x4*)pb, b1 = *(const f32x4*)(pb + 4);
    f16x8 r;
    r[0] = (_Float16)((a0[0]+b0[0])*sc); r[1] = (_Float16)((a0[1]+b0[1])*sc);
    r[2] = (_Float16)((a0[2]+b0[2])*sc); r[3] = (_Float16)((a0[3]+b0[3])*sc);
    r[4] = (_Float16)((a1[0]+b1[0])*sc); r[5] = (_Float16)((a1[1]+b1[1])*sc);
    r[6] = (_Float16)((a1[2]+b1[2])*sc); r[7] = (_Float16)((a1[3]+b1[3])*sc);
    return r;
}
__device__ __forceinline__ f32x4 biasTile(const float* ba, int off, int g, float sc) {
    f32x4 a = *(const f32x4*)(ba + off + 4 * g);
    return (f32x4){a[0]*sc, a[1]*sc, a[2]*sc, a[3]*sc};
}
__device__ __forceinline__ f32x4 biasTile2(const float* ba, const float* bb, int off, int g, float sc) {
    f32x4 a = *(const f32x4*)(ba + off + 4 * g);
    f32x4 b = *(const f32x4*)(bb + off + 4 * g);
    return (f32x4){(a[0]+b[0])*sc, (a[1]+b[1])*sc, (a[2]+b[2])*sc, (a[3]+b[3])*sc};
}

struct ETiles { f32x4 r0, r1, z0, z1, nx0, nx1; };

// 512-thread block = 8 independent waves (2 per SIMD) -> co-resident waves
// fill each other's latency bubbles. Each wave = 16 batch elements, fully
// independent (no __syncthreads). Body identical to R9.
__global__ __launch_bounds__(WPB * 64) __attribute__((amdgpu_waves_per_eu(2, 2)))
void gru_encdec(
    const float* __restrict__ x,
    const float* __restrict__ W_emb, const float* __restrict__ b_emb,
    const float* __restrict__ Wih_e, const float* __restrict__ Whh_e,
    const float* __restrict__ bih_e, const float* __restrict__ bhh_e,
    const float* __restrict__ Wih_d, const float* __restrict__ Whh_d,
    const float* __restrict__ bih_d, const float* __restrict__ bhh_d,
    const float* __restrict__ W_out, const float* __restrict__ b_out,
    float* __restrict__ y)
{
    const int l = threadIdx.x & 63;
    const int s = l & 15;
    const int g = l >> 4;
    const int w = blockIdx.x * WPB + (threadIdx.x >> 6);   // wave id = batch group

    // ---- encoder A-fragments (prescaled: r,z by log2e; n by 2log2e) ----
    const f16x8 Axr0 = loadAfrag(Wih_e,  0, s, g, L2E), Axr1 = loadAfrag(Wih_e, 16, s, g, L2E);
    const f16x8 Axz0 = loadAfrag(Wih_e, 32, s, g, L2E), Axz1 = loadAfrag(Wih_e, 48, s, g, L2E);
    const f16x8 Axn0 = loadAfrag(Wih_e, 64, s, g, N2E), Axn1 = loadAfrag(Wih_e, 80, s, g, N2E);
    const f16x8 Ahr0 = loadAfrag(Whh_e,  0, s, g, L2E), Ahr1 = loadAfrag(Whh_e, 16, s, g, L2E);
    const f16x8 Ahz0 = loadAfrag(Whh_e, 32, s, g, L2E), Ahz1 = loadAfrag(Whh_e, 48, s, g, L2E);
    const f16x8 Ahn0 = loadAfrag(Whh_e, 64, s, g, N2E), Ahn1 = loadAfrag(Whh_e, 80, s, g, N2E);

    const f32x4 Tbr0  = biasTile2(bih_e, bhh_e,  0, g, L2E), Tbr1 = biasTile2(bih_e, bhh_e, 16, g, L2E);
    const f32x4 Tbz0  = biasTile2(bih_e, bhh_e, 32, g, L2E), Tbz1 = biasTile2(bih_e, bhh_e, 48, g, L2E);
    const f32x4 Tbnx0 = biasTile(bih_e, 64, g, N2E), Tbnx1 = biasTile(bih_e, 80, g, N2E);
    const f32x4 Tbnh0 = biasTile(bhh_e, 64, g, N2E), Tbnh1 = biasTile(bhh_e, 80, g, N2E);

    // ---- embedder weights (unscaled; e is an activation) ----
    f16x2 wemb[8][2]; float bemb8[8];
    #pragma unroll
    for (int kk = 0; kk < 8; ++kk) {
        const f32x4 v = *(const f32x4*)(W_emb + (size_t)(g * 8 + kk) * 4);
        wemb[kk][0] = pkrtz(v[0], v[1]);
        wemb[kk][1] = pkrtz(v[2], v[3]);
        bemb8[kk] = b_emb[g * 8 + kk];
    }

    const f32x4* xb = (const f32x4*)x + (size_t)(w * ELW + s) * T_LEN;

    auto make_eB = [&](const f32x4 xv) -> f16x8 {
        const f16x2 xp01 = pkrtz(xv[0], xv[1]);
        const f16x2 xp23 = pkrtz(xv[2], xv[3]);
        float ev[8];
        #pragma unroll
        for (int kk = 0; kk < 8; ++kk)
            ev[kk] = fmaxf(dot2(wemb[kk][0], xp01, dot2(wemb[kk][1], xp23, bemb8[kk])), 0.0f);
        F16x8U e;
        #pragma unroll
        for (int q = 0; q < 4; ++q)
            e.d[q] = pkbits(ev[2 * q], ev[2 * q + 1]);
        return e.v;
    };
    auto make_E = [&](f16x8 eB) -> ETiles {
        ETiles E;
        E.nx0 = MF(Axn0, eB, Tbnx0); E.nx1 = MF(Axn1, eB, Tbnx1);
        E.r0  = MF(Axr0, eB, Tbr0);  E.r1  = MF(Axr1, eB, Tbr1);
        E.z0  = MF(Axz0, eB, Tbz0);  E.z1  = MF(Axz1, eB, Tbz1);
        return E;
    };

    F16x8U hB; hB.d[0] = 0; hB.d[1] = 0; hB.d[2] = 0; hB.d[3] = 0;
    f32x4 hc0 = {0.f, 0.f, 0.f, 0.f};
    f32x4 hc1 = {0.f, 0.f, 0.f, 0.f};

    // ---- pipeline prologue ----
    f32x4 x0 = xb[0], x1 = xb[1], xc = xb[2], xd = xb[3];
    ETiles E = make_E(make_eB(x0));   // e-tiles for step 0
    f16x8 eBn = make_eB(x1);          // e-fragment for step 1

    // ---- encoder: 512 steps ----
    #pragma unroll 1
    for (int t = 0; t < T_LEN; ++t) {
        // chain head: h-MFMAs (n-path first, z last)
        const f32x4 cnh0 = MF(Ahn0, hB.v, Tbnh0), cnh1 = MF(Ahn1, hB.v, Tbnh1);
        const f32x4 cr0  = MF(Ahr0, hB.v, E.r0),  cr1  = MF(Ahr1, hB.v, E.r1);
        const f32x4 cz0  = MF(Ahz0, hB.v, E.z0),  cz1  = MF(Ahz1, hB.v, E.z1);
        const f32x4 cnx0 = E.nx0, cnx1 = E.nx1;
        // off-chain: next step's e-tiles + next-next e-fragment + x prefetch
        E = make_E(eBn);
        eBn = make_eB(xc);
        xc = xd;
        int ti = t + 4; ti = ti < T_LEN ? ti : T_LEN - 1;
        xd = xb[ti];
        // gates (prescaled inputs, native exp2)
        #pragma unroll
        for (int i = 0; i < 4; ++i) {
            const float r0 = sig_s(cr0[i]), z0 = sig_s(cz0[i]);
            const float n0 = tanh_s(fmaf(r0, cnh0[i], cnx0[i]));
            hc0[i] = fmaf(z0, hc0[i] - n0, n0);
            const float r1 = sig_s(cr1[i]), z1 = sig_s(cz1[i]);
            const float n1 = tanh_s(fmaf(r1, cnh1[i], cnx1[i]));
            hc1[i] = fmaf(z1, hc1[i] - n1, n1);
        }
        // C-layout -> B-fragment (all-VALU transpose)
        unsigned p0 = pkbits(hc0[0], hc0[1]), p1 = pkbits(hc0[2], hc0[3]);
        unsigned q0 = pkbits(hc1[0], hc1[1]), q1 = pkbits(hc1[2], hc1[3]);
        swap32(p0, q0); swap32(p1, q1);
        swap16(p0, q0); swap16(p1, q1);
        hB.d[0] = p0; hB.d[1] = p1; hB.d[2] = q0; hB.d[3] = q1;
    }

    // ---- decoder A-fragments (r,z presummed; prescaled) + W_out ----
    const f16x8 Adr0 = loadAfragSum(Wih_d, Whh_d,  0, s, g, L2E);
    const f16x8 Adr1 = loadAfragSum(Wih_d, Whh_d, 16, s, g, L2E);
    const f16x8 Adz0 = loadAfragSum(Wih_d, Whh_d, 32, s, g, L2E);
    const f16x8 Adz1 = loadAfragSum(Wih_d, Whh_d, 48, s, g, L2E);
    const f16x8 Adnx0 = loadAfrag(Wih_d, 64, s, g, N2E), Adnx1 = loadAfrag(Wih_d, 80, s, g, N2E);
    const f16x8 Adnh0 = loadAfrag(Whh_d, 64, s, g, N2E), Adnh1 = loadAfrag(Whh_d, 80, s, g, N2E);
    f16x8 Aout = {};
    if (s < 4) Aout = loadAfrag(W_out, 0, s, g, 1.0f);
    const f32x4 Tdr0  = biasTile2(bih_d, bhh_d,  0, g, L2E), Tdr1 = biasTile2(bih_d, bhh_d, 16, g, L2E);
    const f32x4 Tdz0  = biasTile2(bih_d, bhh_d, 32, g, L2E), Tdz1 = biasTile2(bih_d, bhh_d, 48, g, L2E);
    const f32x4 Tdnx0 = biasTile(bih_d, 64, g, N2E), Tdnx1 = biasTile(bih_d, 80, g, N2E);
    const f32x4 Tdnh0 = biasTile(bhh_d, 64, g, N2E), Tdnh1 = biasTile(bhh_d, 80, g, N2E);
    const f32x4 Tby = (g == 0) ? *(const f32x4*)b_out : (f32x4){0.f, 0.f, 0.f, 0.f};

    // ---- decoder: 60 steps ----
    #pragma unroll 1
    for (int f = 0; f < FUT; ++f) {
        const f32x4 cnh0 = MF(Adnh0, hB.v, Tdnh0), cnh1 = MF(Adnh1, hB.v, Tdnh1);
        const f32x4 cr0  = MF(Adr0, hB.v, Tdr0),   cr1  = MF(Adr1, hB.v, Tdr1);
        const f32x4 cnx0 = MF(Adnx0, hB.v, Tdnx0), cnx1 = MF(Adnx1, hB.v, Tdnx1);
        const f32x4 cz0  = MF(Adz0, hB.v, Tdz0),   cz1  = MF(Adz1, hB.v, Tdz1);
        #pragma unroll
        for (int i = 0; i < 4; ++i) {
            const float r0 = sig_s(cr0[i]), z0 = sig_s(cz0[i]);
            const float n0 = tanh_s(fmaf(r0, cnh0[i], cnx0[i]));
            hc0[i] = fmaf(z0, hc0[i] - n0, n0);
            const float r1 = sig_s(cr1[i]), z1 = sig_s(cz1[i]);
            const float n1 = tanh_s(fmaf(r1, cnh1[i], cnx1[i]));
            hc1[i] = fmaf(z1, hc1[i] - n1, n1);
        }
        unsigned p0 = pkbits(hc0[0], hc0[1]), p1 = pkbits(hc0[2], hc0[3]);
        unsigned q0 = pkbits(hc1[0], hc1[1]), q1 = pkbits(hc1[2], hc1[3]);
        swap32(p0, q0); swap32(p1, q1);
        swap16(p0, q0); swap16(p1, q1);
        hB.d[0] = p0; hB.d[1] = p1; hB.d[2] = q0; hB.d[3] = q1;

        const f32x4 cy = MF(Aout, hB.v, Tby);
        if (g == 0)
            *(f32x4*)(y + ((size_t)(w * ELW + s) * FUT + f) * 4) = cy;
    }
}

extern "C" void kernel_launch(void* const* d_in, const int* in_sizes, int n_in,
                              void* d_out, int out_size, void* d_ws, size_t ws_size,
                              hipStream_t stream) {
    (void)in_sizes; (void)n_in; (void)d_ws; (void)ws_size; (void)out_size;
    gru_encdec<<<dim3(2048 / (ELW * WPB)), dim3(WPB * 64), 0, stream>>>(
        (const float*)d_in[0],                            // x
        (const float*)d_in[1],  (const float*)d_in[2],    // W_emb, b_emb
        (const float*)d_in[3],  (const float*)d_in[4],    // Wih_e, Whh_e
        (const float*)d_in[5],  (const float*)d_in[6],    // bih_e, bhh_e
        (const float*)d_in[7],  (const float*)d_in[8],    // Wih_d, Whh_d
        (const float*)d_in[9],  (const float*)d_in[10],   // bih_d, bhh_d
        (const float*)d_in[11], (const float*)d_in[12],   // W_out, b_out
        (float*)d_out);
}